// Round 2
// baseline (12408.400 us; speedup 1.0000x reference)
//
#include <hip/hip_runtime.h>
#include <hip/hip_bf16.h>

// Per-sample slot stride (floats): padded SAME buffer 32ch x 146 x 20
#define REG 93440

// ---------------------------------------------------------------------------
// Weight repack: [co][ci][kh][kw] -> [ci][k][co] with BN scale folded in.
// Also emits per-channel shift t[co] = (b-m)*s + be,  s = g*rsqrt(v+eps).
// ---------------------------------------------------------------------------
__global__ void repack_k(const float* __restrict__ W, const float* __restrict__ bb,
                         const float* __restrict__ gg, const float* __restrict__ be,
                         const float* __restrict__ mm, const float* __restrict__ vv,
                         float* __restrict__ wOut, float* __restrict__ tOut,
                         int CIN, int KHW, int COUT)
{
    int gid = blockIdx.x * 256 + threadIdx.x;
    if (gid < COUT) {
        float s = gg[gid] * rsqrtf(vv[gid] + 1e-5f);
        tOut[gid] = (bb[gid] - mm[gid]) * s + be[gid];
    }
    int tot = CIN * KHW * COUT;
    if (gid >= tot) return;
    int co = gid % COUT;
    int rest = gid / COUT;       // ci*KHW + k
    int k = rest % KHW;
    int ci = rest / KHW;
    float s = gg[co] * rsqrtf(vv[co] + 1e-5f);
    wOut[gid] = W[(co * CIN + ci) * KHW + k] * s;
}

// ---------------------------------------------------------------------------
// Zero the pad rings of both padded ping-pong buffers (rows 0/145 full width,
// cols 0 and 16 for rows 1..144), per sample, per 32 channels.
// ---------------------------------------------------------------------------
__global__ void zero_rings_k(float* __restrict__ bufA, float* __restrict__ bufB, int cn)
{
    int gid = blockIdx.x * 256 + threadIdx.x;
    int tot = cn * 2 * 32 * 328;
    if (gid >= tot) return;
    int e = gid % 328;
    int rest = gid / 328;
    int ch = rest % 32; rest /= 32;
    int bsel = rest & 1;
    int nl = rest >> 1;
    float* base = (bsel ? bufB : bufA) + (size_t)nl * REG + ch * 2920;
    int row, col;
    if (e < 40) { row = (e < 20) ? 0 : 145; col = (e < 20) ? e : e - 20; }
    else { int e2 = e - 40; row = 1 + (e2 >> 1); col = (e2 & 1) ? 16 : 0; }
    base[row * 20 + col] = 0.f;
}

// ---------------------------------------------------------------------------
// Conv1: 1 -> 32 channels, 3x3 SAME, input built on the fly from x windows.
// out is the padded (32,146,20) buffer.
// NOTE: two distinct zero paddings on the window axis: (a) conv SAME padding
// at window cols -1 and 15 (must be zero ALWAYS), (b) the T-padding baked
// into window extraction (zero when t+c-7 outside [0,108)). Check both.
// ---------------------------------------------------------------------------
__global__ __launch_bounds__(256) void conv1_k(
    const float* __restrict__ x, float* __restrict__ out,
    const float* __restrict__ wr, const float* __restrict__ tv,
    int c0, int cn)
{
    int gid = blockIdx.x * 256 + threadIdx.x;
    if (gid >= cn * 2160) return;
    int nl = gid / 2160, p = gid - nl * 2160;
    int f = p / 15, w = p - f * 15;
    int n = c0 + nl;
    int b = n / 108, t = n - b * 108;

    float acc[32];
#pragma unroll
    for (int i = 0; i < 32; ++i) acc[i] = 0.f;

    for (int kh = 0; kh < 3; ++kh) {
        int ff = f + kh - 1;
        if (ff < 0 || ff >= 144) continue;
        for (int kw = 0; kw < 3; ++kw) {
            int c = w + kw - 1;               // window column
            if (c < 0 || c >= 15) continue;   // conv SAME pad -> zero
            int tt = t + c - 7;
            if (tt < 0 || tt >= 108) continue; // window T-pad -> zero
            float xval = x[(b * 108 + tt) * 144 + ff];
            const float* wp = wr + (kh * 3 + kw) * 32;
#pragma unroll
            for (int q = 0; q < 8; ++q) {
                float4 wv = *(const float4*)(wp + q * 4);
                acc[q * 4 + 0] = fmaf(xval, wv.x, acc[q * 4 + 0]);
                acc[q * 4 + 1] = fmaf(xval, wv.y, acc[q * 4 + 1]);
                acc[q * 4 + 2] = fmaf(xval, wv.z, acc[q * 4 + 2]);
                acc[q * 4 + 3] = fmaf(xval, wv.w, acc[q * 4 + 3]);
            }
        }
    }
    float* ob = out + (size_t)nl * REG + (f + 1) * 20 + (w + 1);
#pragma unroll
    for (int co = 0; co < 32; ++co)
        ob[co * 2920] = fmaxf(acc[co] + tv[co], 0.f);
}

// ---------------------------------------------------------------------------
// Generic 3x3 conv (+optional fused 2x1 maxpool over rows).
// Thread micro-tile: 8 cout x 8 adjacent cols (w0 in {0,8}), one row.
// Aligned float4 loads everywhere. Garbage cols only ever feed masked outputs.
// ---------------------------------------------------------------------------
template<int CIN, int COUT, int IWS, int ICH, int OH, int OW,
         int OIWS, int OCH, int OOFF, int CG, int ROWS, bool POOL>
__global__ __launch_bounds__(CG * 2 * ROWS) void convk(
    const float* __restrict__ in, float* __restrict__ out,
    const float* __restrict__ wr, const float* __restrict__ tv)
{
    constexpr int CGS = (CG == 4) ? 2 : 3;
    const int tid = threadIdx.x;
    const int cg = tid & (CG - 1);
    const int wh = (tid >> CGS) & 1;
    const int row = tid >> (CGS + 1);
    const int r = blockIdx.x * ROWS + row;
    const int n = blockIdx.y;
    const int w0 = wh ? 8 : 0;
    const float* inN = in + (size_t)n * REG;

    float acc[8][8];
#pragma unroll
    for (int a = 0; a < 8; ++a)
#pragma unroll
        for (int b2 = 0; b2 < 8; ++b2) acc[a][b2] = 0.f;

    for (int ci = 0; ci < CIN; ++ci) {
        const float* ip = inN + ci * ICH + r * IWS + w0;
#pragma unroll
        for (int kh = 0; kh < 3; ++kh) {
            const float4* p4 = (const float4*)(ip + kh * IWS);
            float4 A = p4[0], Bv = p4[1], Cv = p4[2];
            float xv[12] = {A.x, A.y, A.z, A.w, Bv.x, Bv.y, Bv.z, Bv.w,
                            Cv.x, Cv.y, Cv.z, Cv.w};
            const float* wp = wr + ((ci * 3 + kh) * 3) * COUT + cg * 8;
#pragma unroll
            for (int kw = 0; kw < 3; ++kw) {
                float4 wA = *(const float4*)(wp + kw * COUT);
                float4 wB = *(const float4*)(wp + kw * COUT + 4);
#pragma unroll
                for (int j = 0; j < 8; ++j) {
                    float xx = xv[j + kw];
                    acc[0][j] = fmaf(xx, wA.x, acc[0][j]);
                    acc[1][j] = fmaf(xx, wA.y, acc[1][j]);
                    acc[2][j] = fmaf(xx, wA.z, acc[2][j]);
                    acc[3][j] = fmaf(xx, wA.w, acc[3][j]);
                    acc[4][j] = fmaf(xx, wB.x, acc[4][j]);
                    acc[5][j] = fmaf(xx, wB.y, acc[5][j]);
                    acc[6][j] = fmaf(xx, wB.z, acc[6][j]);
                    acc[7][j] = fmaf(xx, wB.w, acc[7][j]);
                }
            }
        }
    }

    const int orow = POOL ? (r >> 1) : r;
    float* outN = out + (size_t)n * REG;
#pragma unroll
    for (int co = 0; co < 8; ++co) {
        const int coa = cg * 8 + co;
        const float tb = tv[coa];
        float* ob = outN + coa * OCH + (orow + OOFF) * OIWS + (w0 + OOFF);
#pragma unroll
        for (int j = 0; j < 8; ++j) {
            float vv = fmaxf(acc[co][j] + tb, 0.f);
            if (POOL) {
                float o = __shfl_xor(vv, CG * 2);
                vv = fmaxf(vv, o);
            }
            bool st = (r < OH) && (w0 + j < OW);
            if (POOL) st = st && ((r & 1) == 0);
            if (st) ob[j] = vv;
        }
    }
}

// ---------------------------------------------------------------------------
// Conv7: 64 -> 128 channels, 12x9 VALID on (34,11). One block per sample,
// input staged in LDS in two 32-channel halves. Weights stream from L2.
// Thread micro-tile: 8 cout x 5 positions (stride 16 over 69 positions).
// ---------------------------------------------------------------------------
__global__ __launch_bounds__(256) void conv7_k(
    const float* __restrict__ in, float* __restrict__ out,
    const float* __restrict__ wr, const float* __restrict__ tv)
{
    __shared__ __align__(16) float sIn[13056];  // 32ch x 34 x 12
    const int n = blockIdx.x;
    const int tid = threadIdx.x;
    const int cg = tid & 15, pg = tid >> 4;

    int base[5], sb[5];
    bool val[5];
#pragma unroll
    for (int i = 0; i < 5; ++i) {
        int p = pg + 16 * i;
        val[i] = p < 69;
        int pc = val[i] ? p : 0;
        int h = pc / 3, w = pc - h * 3;
        base[i] = h * 12 + w;
        sb[i] = h * 4 + w;
    }
    float acc[5][8];
#pragma unroll
    for (int i = 0; i < 5; ++i)
#pragma unroll
        for (int c = 0; c < 8; ++c) acc[i][c] = 0.f;

    const float4* g4 = (const float4*)(in + (size_t)n * REG);
    for (int half = 0; half < 2; ++half) {
        __syncthreads();
        float4* s4 = (float4*)sIn;
        for (int i = tid; i < 3264; i += 256) s4[i] = g4[half * 3264 + i];
        __syncthreads();
        for (int cil = 0; cil < 32; ++cil) {
            int ci = half * 32 + cil;
            const float* sc = sIn + cil * 408;
            const float* wpc = wr + (size_t)ci * 108 * 128 + cg * 8;
            for (int kh = 0; kh < 12; ++kh) {
                const float* sch = sc + kh * 12;
                const float* wph = wpc + kh * 9 * 128;
#pragma unroll
                for (int kw = 0; kw < 9; ++kw) {
                    float4 wA = *(const float4*)(wph + kw * 128);
                    float4 wB = *(const float4*)(wph + kw * 128 + 4);
#pragma unroll
                    for (int i = 0; i < 5; ++i) {
                        float xx = sch[base[i] + kw];
                        acc[i][0] = fmaf(xx, wA.x, acc[i][0]);
                        acc[i][1] = fmaf(xx, wA.y, acc[i][1]);
                        acc[i][2] = fmaf(xx, wA.z, acc[i][2]);
                        acc[i][3] = fmaf(xx, wA.w, acc[i][3]);
                        acc[i][4] = fmaf(xx, wB.x, acc[i][4]);
                        acc[i][5] = fmaf(xx, wB.y, acc[i][5]);
                        acc[i][6] = fmaf(xx, wB.z, acc[i][6]);
                        acc[i][7] = fmaf(xx, wB.w, acc[i][7]);
                    }
                }
            }
        }
    }

    float* outN = out + (size_t)n * REG;
#pragma unroll
    for (int i = 0; i < 5; ++i) {
        if (!val[i]) continue;
#pragma unroll
        for (int co = 0; co < 8; ++co) {
            int coa = cg * 8 + co;
            outN[coa * 92 + sb[i]] = fmaxf(acc[i][co] + tv[coa], 0.f);
        }
    }
}

// ---------------------------------------------------------------------------
// Spatial mean over the 23x3 positions of h7 (stored 23 x 4, col 3 slack).
// ---------------------------------------------------------------------------
__global__ void mean_k(const float* __restrict__ in, float* __restrict__ outp, int cn)
{
    int gid = blockIdx.x * 256 + threadIdx.x;
    if (gid >= cn * 128) return;
    int nl = gid >> 7, ci = gid & 127;
    const float4* p = (const float4*)(in + (size_t)nl * REG + ci * 92);
    float s = 0.f;
#pragma unroll
    for (int r = 0; r < 23; ++r) { float4 v = p[r]; s += v.x + v.y + v.z; }
    outp[(size_t)nl * REG + ci] = s * (1.f / 69.f);
}

// ---------------------------------------------------------------------------
// logits = b8 + W8(25x128) . pooled  (1x1 conv commuted past the mean)
// ---------------------------------------------------------------------------
__global__ void logits_k(const float* __restrict__ pooled, const float* __restrict__ W8,
                         const float* __restrict__ b8, float* __restrict__ outg,
                         int c0, int cn)
{
    int gid = blockIdx.x * 256 + threadIdx.x;
    if (gid >= cn * 25) return;
    int nl = gid / 25, c = gid - nl * 25;
    const float* pp = pooled + (size_t)nl * REG;
    const float* wp = W8 + c * 128;
    float s = b8[c];
#pragma unroll
    for (int ci = 0; ci < 128; ci += 4) {
        float4 wv = *(const float4*)(wp + ci);
        float4 pv = *(const float4*)(pp + ci);
        s = fmaf(wv.x, pv.x, s);
        s = fmaf(wv.y, pv.y, s);
        s = fmaf(wv.z, pv.z, s);
        s = fmaf(wv.w, pv.w, s);
    }
    outg[(size_t)(c0 + nl) * 25 + c] = s;
}

// ---------------------------------------------------------------------------
extern "C" void kernel_launch(void* const* d_in, const int* in_sizes, int n_in,
                              void* d_out, int out_size, void* d_ws, size_t ws_size,
                              hipStream_t stream)
{
    const float* x = (const float*)d_in[0];
    // labels = d_in[1], unused
    const float* Wl[8]; const float* bl[8]; const float* gl[8];
    const float* bel[8]; const float* ml[8]; const float* vl[8];
    for (int i = 1; i <= 7; ++i) {
        int o = 2 + (i - 1) * 6;
        Wl[i]  = (const float*)d_in[o + 0];
        bl[i]  = (const float*)d_in[o + 1];
        gl[i]  = (const float*)d_in[o + 2];
        bel[i] = (const float*)d_in[o + 3];
        ml[i]  = (const float*)d_in[o + 4];
        vl[i]  = (const float*)d_in[o + 5];
    }
    const float* W8 = (const float*)d_in[44];
    const float* b8 = (const float*)d_in[45];
    float* ws = (float*)d_ws;

    // Workspace layout (float offsets); all 16B aligned.
    float* wr1 = ws + 0;     float* t1 = ws + 288;
    float* wr2 = ws + 320;   float* t2 = ws + 9536;
    float* wr3 = ws + 9568;  float* t3 = ws + 18784;
    float* wr4 = ws + 18816; float* t4 = ws + 28032;
    float* wr5 = ws + 28064; float* t5 = ws + 46496;
    float* wr6 = ws + 46560; float* t6 = ws + 83424;
    float* wr7 = ws + 83488; float* t7 = ws + 968224;
    const size_t WFL = 968384;

    size_t avail_fl = ws_size / 4;
    size_t buf_fl = (avail_fl > WFL) ? (avail_fl - WFL) : 0;
    int Cs = (int)(buf_fl / (2 * (size_t)REG));
    if (Cs < 1) Cs = 1;
    if (Cs > 1728) Cs = 1728;
    float* bufA = ws + WFL;
    float* bufB = bufA + (size_t)Cs * REG;

    auto g1 = [](int t) { return (t + 255) / 256; };

    // Weight repacks (once per call)
    repack_k<<<g1(288),    256, 0, stream>>>(Wl[1], bl[1], gl[1], bel[1], ml[1], vl[1], wr1, t1, 1,  9,  32);
    repack_k<<<g1(9216),   256, 0, stream>>>(Wl[2], bl[2], gl[2], bel[2], ml[2], vl[2], wr2, t2, 32, 9,  32);
    repack_k<<<g1(9216),   256, 0, stream>>>(Wl[3], bl[3], gl[3], bel[3], ml[3], vl[3], wr3, t3, 32, 9,  32);
    repack_k<<<g1(9216),   256, 0, stream>>>(Wl[4], bl[4], gl[4], bel[4], ml[4], vl[4], wr4, t4, 32, 9,  32);
    repack_k<<<g1(18432),  256, 0, stream>>>(Wl[5], bl[5], gl[5], bel[5], ml[5], vl[5], wr5, t5, 32, 9,  64);
    repack_k<<<g1(36864),  256, 0, stream>>>(Wl[6], bl[6], gl[6], bel[6], ml[6], vl[6], wr6, t6, 64, 9,  64);
    repack_k<<<g1(884736), 256, 0, stream>>>(Wl[7], bl[7], gl[7], bel[7], ml[7], vl[7], wr7, t7, 64, 108, 128);

    for (int c0 = 0; c0 < 1728; c0 += Cs) {
        int cn = (1728 - c0 < Cs) ? (1728 - c0) : Cs;
        zero_rings_k<<<g1(cn * 20992), 256, 0, stream>>>(bufA, bufB, cn);
        conv1_k<<<g1(cn * 2160), 256, 0, stream>>>(x, bufA, wr1, t1, c0, cn);
        // L2: 32->32 SAME on padded (146,20) -> padded
        convk<32, 32, 20, 2920, 144, 15, 20, 2920, 1, 4, 24, false>
            <<<dim3(6, cn), 192, 0, stream>>>(bufA, bufB, wr2, t2);
        // L3
        convk<32, 32, 20, 2920, 144, 15, 20, 2920, 1, 4, 24, false>
            <<<dim3(6, cn), 192, 0, stream>>>(bufB, bufA, wr3, t3);
        // L4 + pool -> (32,72,16) tight
        convk<32, 32, 20, 2920, 144, 15, 16, 1152, 0, 4, 24, true>
            <<<dim3(6, cn), 192, 0, stream>>>(bufA, bufB, wr4, t4);
        // L5 VALID: (32,72,16) -> (64,70,16)
        convk<32, 64, 16, 1152, 70, 13, 16, 1120, 0, 8, 16, false>
            <<<dim3(5, cn), 256, 0, stream>>>(bufB, bufA, wr5, t5);
        // L6 VALID + pool: (64,70,16) -> (64,34,12)
        convk<64, 64, 16, 1120, 68, 11, 12, 408, 0, 8, 16, true>
            <<<dim3(5, cn), 256, 0, stream>>>(bufA, bufB, wr6, t6);
        // L7: (64,34,12) -> (128,23,4)
        conv7_k<<<cn, 256, 0, stream>>>(bufB, bufA, wr7, t7);
        mean_k<<<g1(cn * 128), 256, 0, stream>>>(bufA, bufB, cn);
        logits_k<<<g1(cn * 25), 256, 0, stream>>>(bufB, W8, b8, (float*)d_out, c0, cn);
    }
}